// Round 1
// baseline (198.209 us; speedup 1.0000x reference)
//
#include <hip/hip_runtime.h>
#include <hip/hip_bf16.h>
#include <stdint.h>

// Problem constants
#define NBATCH 4
#define SEQ    2048
#define DIM    1024
#define MTOT   (NBATCH*SEQ)   // 8192

typedef __attribute__((ext_vector_type(8))) __bf16 bf16x8;
typedef __attribute__((ext_vector_type(4))) float  f32x4;

// Workspace layout (bytes)
#define OFF_XBF   (0ull)                         // 8192*1024*2       = 16 MiB
#define OFF_WBF   (16777216ull)                  // 3*1024*1024*2     =  6 MiB
#define OFF_Q     (23068672ull)                  // 16 MiB (bf16, pre-scaled by 1/32)
#define OFF_K     (39845888ull)                  // 16 MiB
#define OFF_VT    (56623104ull)                  // 16 MiB  V^T per batch [DIM][SEQ]
#define OFF_SC    (73400320ull)                  // 64 MiB fp32 scores (lower-tri tiles only)
#define OFF_P     (140509184ull)                 // 32 MiB bf16 probs
// total 174,063,616 B

__device__ __forceinline__ uint16_t f2bf(float f) {
  uint32_t u = __float_as_uint(f);
  u = (u + 0x7fffu + ((u >> 16) & 1u)) >> 16;   // RTN-even
  return (uint16_t)u;
}

// ---------------- converts ----------------
__global__ __launch_bounds__(256) void k_convert_x(const float* __restrict__ X,
                                                   uint16_t* __restrict__ Xbf) {
  int i = blockIdx.x * 256 + threadIdx.x;       // 2,097,152 threads, 4 floats each
  float4 v = ((const float4*)X)[i];
  ushort4 o;
  o.x = f2bf(v.x); o.y = f2bf(v.y); o.z = f2bf(v.z); o.w = f2bf(v.w);
  ((ushort4*)Xbf)[i] = o;
}

__global__ __launch_bounds__(256) void k_convert_w(const float* __restrict__ Wq,
                                                   const float* __restrict__ Wk,
                                                   const float* __restrict__ Wv,
                                                   uint16_t* __restrict__ Wbf) {
  int g = blockIdx.y;
  const float* W = (g == 0) ? Wq : (g == 1) ? Wk : Wv;
  float scale = (g == 0) ? 0.03125f : 1.0f;     // fold 1/sqrt(1024) into W_q
  int i = blockIdx.x * 256 + threadIdx.x;       // 262,144 per matrix
  float4 v = ((const float4*)W)[i];
  ushort4 o;
  o.x = f2bf(v.x * scale); o.y = f2bf(v.y * scale);
  o.z = f2bf(v.z * scale); o.w = f2bf(v.w * scale);
  ((ushort4*)(Wbf + (size_t)g * 1048576))[i] = o;
}

// ---------------- shared GEMM core (B^T form) ----------------
// C[128x128] tile, BK=64, 4 waves (2x2), mfma_f32_16x16x32_bf16, acc 4x4 frags/wave.
// LDS tiles are [128 rows][64 bf16] = 128B/row with XOR swizzle:
// logical byte bo -> phys bo ^ ((row&7)<<4). global_load_lds writes linearly, so the
// *source* address is inverse-swizzled (same involution) and ds_reads apply the XOR.

__device__ __forceinline__ void gll16(const void* g, void* l) {
  __builtin_amdgcn_global_load_lds((const __attribute__((address_space(1))) void*)g,
                                   (__attribute__((address_space(3))) void*)l, 16, 0, 0);
}

__device__ __forceinline__ void stage_tile(const uint16_t* __restrict__ g, int ld,
                                           int t, char* lds) {
#pragma unroll
  for (int c = 0; c < 4; ++c) {
    int L = c * 4096 + t * 16;                  // linear LDS byte offset (lane-contiguous)
    int row = L >> 7;                           // 128B per row
    int slot = (t & 7) ^ (row & 7);             // inverse-swizzled source slot
    const uint16_t* src = g + (size_t)row * ld + slot * 8;
    gll16((const void*)src, (void*)(lds + L));
  }
}

__device__ __forceinline__ bf16x8 frag_ld(const char* lds, int row, int kbyte) {
  int bo = row * 128 + kbyte;
  bo ^= (row & 7) << 4;
  return *(const bf16x8*)(lds + bo);
}

__device__ __forceinline__ void gemm_loop(const uint16_t* __restrict__ A, int lda,
                                          const uint16_t* __restrict__ Bm, int ldb,
                                          int ksteps, char* ldsA, char* ldsB,
                                          f32x4 acc[4][4]) {
  const int t = threadIdx.x;
  const int lane = t & 63;
  const int wm = (t >> 6) & 1;
  const int wn = t >> 7;
  const int frow = lane & 15;
  const int fk16 = (lane >> 4) * 16;            // byte offset of this lane-group's k-slice

  for (int kt = 0; kt < ksteps; ++kt) {
    stage_tile(A + kt * 64, lda, t, ldsA);
    stage_tile(Bm + kt * 64, ldb, t, ldsB);
    __syncthreads();                            // drains vmcnt: staged tile visible
#pragma unroll
    for (int ki = 0; ki < 2; ++ki) {
      bf16x8 av[4], bv[4];
#pragma unroll
      for (int mi = 0; mi < 4; ++mi)
        av[mi] = frag_ld(ldsA, wm * 64 + mi * 16 + frow, ki * 64 + fk16);
#pragma unroll
      for (int ni = 0; ni < 4; ++ni)
        bv[ni] = frag_ld(ldsB, wn * 64 + ni * 16 + frow, ki * 64 + fk16);
#pragma unroll
      for (int mi = 0; mi < 4; ++mi)
#pragma unroll
        for (int ni = 0; ni < 4; ++ni)
          acc[mi][ni] = __builtin_amdgcn_mfma_f32_16x16x32_bf16(av[mi], bv[ni],
                                                                acc[mi][ni], 0, 0, 0);
    }
    __syncthreads();                            // all reads done before next stage
  }
}

// ---------------- QKV projection ----------------
__global__ __launch_bounds__(256) void k_qkv(const uint16_t* __restrict__ Xbf,
                                             const uint16_t* __restrict__ Wbf,
                                             uint16_t* __restrict__ Qb,
                                             uint16_t* __restrict__ Kb,
                                             uint16_t* __restrict__ Vt) {
  __shared__ __align__(16) char ldsA[16384];
  __shared__ __align__(16) char ldsB[16384];
  f32x4 zero = {0.f, 0.f, 0.f, 0.f};
  f32x4 acc[4][4];
#pragma unroll
  for (int i = 0; i < 4; ++i)
#pragma unroll
    for (int j = 0; j < 4; ++j) acc[i][j] = zero;

  const int m0 = blockIdx.x * 128, n0 = blockIdx.y * 128, g = blockIdx.z;
  const uint16_t* A = Xbf + (size_t)m0 * DIM;
  const uint16_t* Bm = Wbf + (size_t)g * DIM * DIM + (size_t)n0 * DIM;
  gemm_loop(A, DIM, Bm, DIM, DIM / 64, ldsA, ldsB, acc);

  const int lane = threadIdx.x & 63;
  const int wm = (threadIdx.x >> 6) & 1, wn = threadIdx.x >> 7;
  const int rbase = wm * 64 + (lane >> 4) * 4;  // C row = (lane>>4)*4 + reg
  const int cbase = wn * 64 + (lane & 15);      // C col = lane&15

  if (g < 2) {
    uint16_t* out = (g == 0) ? Qb : Kb;
#pragma unroll
    for (int mi = 0; mi < 4; ++mi)
#pragma unroll
      for (int ni = 0; ni < 4; ++ni) {
        int c = n0 + cbase + ni * 16;
#pragma unroll
        for (int r = 0; r < 4; ++r) {
          int m = m0 + rbase + mi * 16 + r;
          out[(size_t)m * DIM + c] = f2bf(acc[mi][ni][r]);
        }
      }
  } else {
    // write V transposed: Vt[b][e][s]
    const int b = m0 >> 11, sl = m0 & 2047;
#pragma unroll
    for (int mi = 0; mi < 4; ++mi)
#pragma unroll
      for (int ni = 0; ni < 4; ++ni) {
        int e = n0 + cbase + ni * 16;
        int s = sl + rbase + mi * 16;
        ushort4 o;
        o.x = f2bf(acc[mi][ni][0]); o.y = f2bf(acc[mi][ni][1]);
        o.z = f2bf(acc[mi][ni][2]); o.w = f2bf(acc[mi][ni][3]);
        *(ushort4*)(Vt + ((size_t)b * DIM + e) * SEQ + s) = o;
      }
  }
}

// ---------------- causal scores: Sc = Q K^T (lower-tri 128x128 tiles) ----------------
__global__ __launch_bounds__(256) void k_scores(const uint16_t* __restrict__ Qb,
                                                const uint16_t* __restrict__ Kb,
                                                float* __restrict__ Sc) {
  __shared__ __align__(16) char ldsA[16384];
  __shared__ __align__(16) char ldsB[16384];
  int x = blockIdx.x;                 // 0..543
  int b = x / 136, tr = x % 136;
  int qt = 0;
  while ((qt + 1) * (qt + 2) / 2 <= tr) ++qt;
  int kt = tr - qt * (qt + 1) / 2;

  f32x4 zero = {0.f, 0.f, 0.f, 0.f};
  f32x4 acc[4][4];
#pragma unroll
  for (int i = 0; i < 4; ++i)
#pragma unroll
    for (int j = 0; j < 4; ++j) acc[i][j] = zero;

  const uint16_t* A = Qb + ((size_t)b * SEQ + qt * 128) * DIM;
  const uint16_t* Bm = Kb + ((size_t)b * SEQ + kt * 128) * DIM;
  gemm_loop(A, DIM, Bm, DIM, DIM / 64, ldsA, ldsB, acc);

  const int lane = threadIdx.x & 63;
  const int wm = (threadIdx.x >> 6) & 1, wn = threadIdx.x >> 7;
  const int rbase = qt * 128 + wm * 64 + (lane >> 4) * 4;
  const int cbase = kt * 128 + wn * 64 + (lane & 15);
  float* out = Sc + (size_t)b * SEQ * SEQ;
#pragma unroll
  for (int mi = 0; mi < 4; ++mi)
#pragma unroll
    for (int ni = 0; ni < 4; ++ni) {
      int c = cbase + ni * 16;
#pragma unroll
      for (int r = 0; r < 4; ++r)
        out[(size_t)(rbase + mi * 16 + r) * SEQ + c] = acc[mi][ni][r];
    }
}

// ---------------- row softmax (causal), writes bf16 P zero-padded to 128 ----------------
__global__ __launch_bounds__(256) void k_softmax(const float* __restrict__ Sc,
                                                 uint16_t* __restrict__ P) {
  int gid = blockIdx.x;               // 8192 rows
  int b = gid >> 11, q = gid & 2047;
  const float* srow = Sc + ((size_t)b * SEQ + q) * SEQ;
  uint16_t* prow = P + ((size_t)b * SEQ + q) * SEQ;
  int t = threadIdx.x;
  int nv = q + 1;

  float m = -3.4e38f;
  for (int k = t; k < nv; k += 256) m = fmaxf(m, srow[k]);
  __shared__ float redm[4];
#pragma unroll
  for (int o = 32; o > 0; o >>= 1) m = fmaxf(m, __shfl_down(m, o));
  if ((t & 63) == 0) redm[t >> 6] = m;
  __syncthreads();
  m = fmaxf(fmaxf(redm[0], redm[1]), fmaxf(redm[2], redm[3]));

  float s = 0.f;
  for (int k = t; k < nv; k += 256) s += __expf(srow[k] - m);
  __shared__ float reds[4];
#pragma unroll
  for (int o = 32; o > 0; o >>= 1) s += __shfl_down(s, o);
  if ((t & 63) == 0) reds[t >> 6] = s;
  __syncthreads();
  s = reds[0] + reds[1] + reds[2] + reds[3];
  float inv = 1.0f / s;

  int kpad = ((q >> 7) + 1) << 7;     // PV reads exactly [0, kpad)
  for (int k = t; k < kpad; k += 256) {
    float p = (k < nv) ? __expf(srow[k] - m) * inv : 0.f;
    prow[k] = f2bf(p);
  }
}

// ---------------- PV: O = P V  (A=P, B=Vt rows=e, cols=k) ----------------
__global__ __launch_bounds__(256) void k_pv(const uint16_t* __restrict__ P,
                                            const uint16_t* __restrict__ Vt,
                                            float* __restrict__ O) {
  __shared__ __align__(16) char ldsA[16384];
  __shared__ __align__(16) char ldsB[16384];
  int x = blockIdx.x;                 // 512
  int b = x >> 7, r7 = x & 127;
  int qt = 15 - (r7 >> 3);            // descending: big K-loops dispatch first
  int et = r7 & 7;

  f32x4 zero = {0.f, 0.f, 0.f, 0.f};
  f32x4 acc[4][4];
#pragma unroll
  for (int i = 0; i < 4; ++i)
#pragma unroll
    for (int j = 0; j < 4; ++j) acc[i][j] = zero;

  const uint16_t* A = P + (size_t)b * SEQ * SEQ + (size_t)qt * 128 * SEQ;
  const uint16_t* Bm = Vt + (size_t)b * DIM * SEQ + (size_t)et * 128 * SEQ;
  gemm_loop(A, SEQ, Bm, SEQ, (qt + 1) * 2, ldsA, ldsB, acc);

  const int lane = threadIdx.x & 63;
  const int wm = (threadIdx.x >> 6) & 1, wn = threadIdx.x >> 7;
  const int rbase = qt * 128 + wm * 64 + (lane >> 4) * 4;
  const int cbase = et * 128 + wn * 64 + (lane & 15);
  float* out = O + (size_t)b * SEQ * DIM;
#pragma unroll
  for (int mi = 0; mi < 4; ++mi)
#pragma unroll
    for (int ni = 0; ni < 4; ++ni) {
      int c = cbase + ni * 16;
#pragma unroll
      for (int r = 0; r < 4; ++r)
        out[(size_t)(rbase + mi * 16 + r) * DIM + c] = acc[mi][ni][r];
    }
}

extern "C" void kernel_launch(void* const* d_in, const int* in_sizes, int n_in,
                              void* d_out, int out_size, void* d_ws, size_t ws_size,
                              hipStream_t stream) {
  const float* X  = (const float*)d_in[0];
  const float* Wq = (const float*)d_in[1];
  const float* Wk = (const float*)d_in[2];
  const float* Wv = (const float*)d_in[3];
  char* ws = (char*)d_ws;
  uint16_t* Xbf = (uint16_t*)(ws + OFF_XBF);
  uint16_t* Wbf = (uint16_t*)(ws + OFF_WBF);
  uint16_t* Qb  = (uint16_t*)(ws + OFF_Q);
  uint16_t* Kb  = (uint16_t*)(ws + OFF_K);
  uint16_t* Vt  = (uint16_t*)(ws + OFF_VT);
  float*    Sc  = (float*)(ws + OFF_SC);
  uint16_t* P   = (uint16_t*)(ws + OFF_P);
  float*    O   = (float*)d_out;

  k_convert_x<<<8192, 256, 0, stream>>>(X, Xbf);
  k_convert_w<<<dim3(1024, 3), 256, 0, stream>>>(Wq, Wk, Wv, Wbf);
  k_qkv<<<dim3(64, 8, 3), 256, 0, stream>>>(Xbf, Wbf, Qb, Kb, Vt);
  k_scores<<<544, 256, 0, stream>>>(Qb, Kb, Sc);
  k_softmax<<<8192, 256, 0, stream>>>(Sc, P);
  k_pv<<<512, 256, 0, stream>>>(P, Vt, O);
}

// Round 2
// 178.249 us; speedup vs baseline: 1.1120x; 1.1120x over previous
//
#include <hip/hip_runtime.h>
#include <hip/hip_bf16.h>
#include <stdint.h>

// Problem constants
#define NBATCH 4
#define SEQ    2048
#define DIM    1024
#define MTOT   (NBATCH*SEQ)   // 8192

typedef __attribute__((ext_vector_type(8))) __bf16 bf16x8;
typedef __attribute__((ext_vector_type(4))) float  f32x4;

// Workspace layout (bytes)
#define OFF_XBF   (0ull)                         // 16 MiB
#define OFF_WBF   (16777216ull)                  //  6 MiB
#define OFF_Q     (23068672ull)                  // 16 MiB (bf16, pre-scaled by 1/32)
#define OFF_K     (39845888ull)                  // 16 MiB
#define OFF_VT    (56623104ull)                  // 16 MiB  V^T per batch [DIM][SEQ]
#define OFF_SC    (73400320ull)                  // 64 MiB fp32 scores
#define OFF_P     (140509184ull)                 // 32 MiB bf16 probs

__device__ __forceinline__ uint16_t f2bf(float f) {
  uint32_t u = __float_as_uint(f);
  u = (u + 0x7fffu + ((u >> 16) & 1u)) >> 16;   // RTN-even
  return (uint16_t)u;
}

// ---------------- converts ----------------
__global__ __launch_bounds__(256) void k_convert_x(const float* __restrict__ X,
                                                   uint16_t* __restrict__ Xbf) {
  int i = blockIdx.x * 256 + threadIdx.x;
  float4 v = ((const float4*)X)[i];
  ushort4 o;
  o.x = f2bf(v.x); o.y = f2bf(v.y); o.z = f2bf(v.z); o.w = f2bf(v.w);
  ((ushort4*)Xbf)[i] = o;
}

__global__ __launch_bounds__(256) void k_convert_w(const float* __restrict__ Wq,
                                                   const float* __restrict__ Wk,
                                                   const float* __restrict__ Wv,
                                                   uint16_t* __restrict__ Wbf) {
  int g = blockIdx.y;
  const float* W = (g == 0) ? Wq : (g == 1) ? Wk : Wv;
  float scale = (g == 0) ? 0.03125f : 1.0f;     // fold 1/sqrt(1024) into W_q
  int i = blockIdx.x * 256 + threadIdx.x;
  float4 v = ((const float4*)W)[i];
  ushort4 o;
  o.x = f2bf(v.x * scale); o.y = f2bf(v.y * scale);
  o.z = f2bf(v.z * scale); o.w = f2bf(v.w * scale);
  ((ushort4*)(Wbf + (size_t)g * 1048576))[i] = o;
}

// ---------------- common LDS helpers ----------------
// LDS rows are 64 bf16 = 128B; XOR swizzle byte_off ^= (row&7)<<4, with the
// inverse permutation applied to the global SOURCE (global_load_lds writes linearly).

__device__ __forceinline__ void gll16(const void* g, void* l) {
  __builtin_amdgcn_global_load_lds((const __attribute__((address_space(1))) void*)g,
                                   (__attribute__((address_space(3))) void*)l, 16, 0, 0);
}

__device__ __forceinline__ bf16x8 frag_ld(const char* lds, int row, int kbyte) {
  int bo = row * 128 + kbyte;
  bo ^= (row & 7) << 4;
  return *(const bf16x8*)(lds + bo);
}

// ============================================================================
// k_qkv: 128(M) x 256(N) tile, BK=64, 512 threads (8 waves, 2M x 4N),
// counted-vmcnt 2-deep double-buffered pipeline (raw s_barrier, never drain
// vmcnt to 0 in steady state). LDS = 2*(16K A + 32K B) = 96 KiB, 1 block/CU.
// ============================================================================

// A half: 128x64 bf16 = 16KB -> 2 loads/thread at 512 threads
__device__ __forceinline__ void stage_A(const uint16_t* __restrict__ g, int ld,
                                        int t, char* lds) {
#pragma unroll
  for (int c = 0; c < 2; ++c) {
    int L = c * 8192 + t * 16;
    int row = L >> 7;
    int slot = (t & 7) ^ (row & 7);
    gll16((const void*)(g + (size_t)row * ld + slot * 8), (void*)(lds + L));
  }
}
// B tile: 256x64 bf16 = 32KB -> 4 loads/thread
__device__ __forceinline__ void stage_B(const uint16_t* __restrict__ g, int ld,
                                        int t, char* lds) {
#pragma unroll
  for (int c = 0; c < 4; ++c) {
    int L = c * 8192 + t * 16;
    int row = L >> 7;
    int slot = (t & 7) ^ (row & 7);
    gll16((const void*)(g + (size_t)row * ld + slot * 8), (void*)(lds + L));
  }
}

#define VM_WAIT6() asm volatile("s_waitcnt vmcnt(6)" ::: "memory")
#define VM_WAIT0() asm volatile("s_waitcnt vmcnt(0)" ::: "memory")
#define RAW_BAR()  asm volatile("s_barrier" ::: "memory")

__global__ __launch_bounds__(512, 2) void k_qkv(const uint16_t* __restrict__ Xbf,
                                                const uint16_t* __restrict__ Wbf,
                                                uint16_t* __restrict__ Qb,
                                                uint16_t* __restrict__ Kb,
                                                uint16_t* __restrict__ Vt) {
  extern __shared__ char lds[];                 // 98304 bytes
  char* la0 = lds;            char* la1 = lds + 16384;
  char* lb0 = lds + 32768;    char* lb1 = lds + 65536;

  const int t = threadIdx.x;
  const int lane = t & 63;
  const int wid = t >> 6;
  const int wm = wid >> 2;                      // 0..1  (64-row strip)
  const int wn = wid & 3;                       // 0..3  (64-col strip)
  const int frow = lane & 15;
  const int fk16 = (lane >> 4) * 16;

  const int m0 = blockIdx.x * 128, n0 = blockIdx.y * 256, g = blockIdx.z;
  const uint16_t* A  = Xbf + (size_t)m0 * DIM;
  const uint16_t* Bm = Wbf + (size_t)g * DIM * DIM + (size_t)n0 * DIM;

  f32x4 zero = {0.f, 0.f, 0.f, 0.f};
  f32x4 acc[4][4];
#pragma unroll
  for (int i = 0; i < 4; ++i)
#pragma unroll
    for (int j = 0; j < 4; ++j) acc[i][j] = zero;

  const int NT = DIM / 64;                      // 16 K-tiles
  // prologue: stage tiles 0 and 1 (12 loads outstanding)
  stage_A(A,       DIM, t, la0); stage_B(Bm,       DIM, t, lb0);
  stage_A(A + 64,  DIM, t, la1); stage_B(Bm + 64,  DIM, t, lb1);

#pragma unroll 2
  for (int kt = 0; kt < NT; ++kt) {
    if (kt == NT - 1) { VM_WAIT0(); } else { VM_WAIT6(); }
    RAW_BAR();                                  // buf[kt&1] fully staged for all waves
    const char* cA = (kt & 1) ? la1 : la0;
    const char* cB = (kt & 1) ? lb1 : lb0;
#pragma unroll
    for (int ki = 0; ki < 2; ++ki) {
      bf16x8 av[4], bv[4];
#pragma unroll
      for (int mi = 0; mi < 4; ++mi)
        av[mi] = frag_ld(cA, wm * 64 + mi * 16 + frow, ki * 64 + fk16);
#pragma unroll
      for (int ni = 0; ni < 4; ++ni)
        bv[ni] = frag_ld(cB, wn * 64 + ni * 16 + frow, ki * 64 + fk16);
#pragma unroll
      for (int mi = 0; mi < 4; ++mi)
#pragma unroll
        for (int ni = 0; ni < 4; ++ni)
          acc[mi][ni] = __builtin_amdgcn_mfma_f32_16x16x32_bf16(av[mi], bv[ni],
                                                                acc[mi][ni], 0, 0, 0);
    }
    RAW_BAR();                                  // all reads of buf[kt&1] complete
    if (kt + 2 < NT) {                          // restage now-free buffer (overlaps kt+1)
      char* nA = (kt & 1) ? la1 : la0;
      char* nB = (kt & 1) ? lb1 : lb0;
      stage_A(A  + (kt + 2) * 64, DIM, t, nA);
      stage_B(Bm + (kt + 2) * 64, DIM, t, nB);
    }
  }

  const int rbase = wm * 64 + (lane >> 4) * 4;  // C row = (lane>>4)*4 + reg
  const int cbase = wn * 64 + (lane & 15);      // C col = lane&15

  if (g < 2) {
    uint16_t* out = (g == 0) ? Qb : Kb;
#pragma unroll
    for (int mi = 0; mi < 4; ++mi)
#pragma unroll
      for (int ni = 0; ni < 4; ++ni) {
        int c = n0 + cbase + ni * 16;
#pragma unroll
        for (int r = 0; r < 4; ++r) {
          int m = m0 + rbase + mi * 16 + r;
          out[(size_t)m * DIM + c] = f2bf(acc[mi][ni][r]);
        }
      }
  } else {
    // write V transposed: Vt[b][e][s]
    const int b = m0 >> 11, sl = m0 & 2047;
#pragma unroll
    for (int mi = 0; mi < 4; ++mi)
#pragma unroll
      for (int ni = 0; ni < 4; ++ni) {
        int e = n0 + cbase + ni * 16;
        int s = sl + rbase + mi * 16;
        ushort4 o;
        o.x = f2bf(acc[mi][ni][0]); o.y = f2bf(acc[mi][ni][1]);
        o.z = f2bf(acc[mi][ni][2]); o.w = f2bf(acc[mi][ni][3]);
        *(ushort4*)(Vt + ((size_t)b * DIM + e) * SEQ + s) = o;
      }
  }
}

// ---------------- 128^2 GEMM core (scores / PV), unchanged this round --------
__device__ __forceinline__ void stage_tile(const uint16_t* __restrict__ g, int ld,
                                           int t, char* lds) {
#pragma unroll
  for (int c = 0; c < 4; ++c) {
    int L = c * 4096 + t * 16;
    int row = L >> 7;
    int slot = (t & 7) ^ (row & 7);
    gll16((const void*)(g + (size_t)row * ld + slot * 8), (void*)(lds + L));
  }
}

__device__ __forceinline__ void gemm_loop(const uint16_t* __restrict__ A, int lda,
                                          const uint16_t* __restrict__ Bm, int ldb,
                                          int ksteps, char* ldsA, char* ldsB,
                                          f32x4 acc[4][4]) {
  const int t = threadIdx.x;
  const int lane = t & 63;
  const int wm = (t >> 6) & 1;
  const int wn = t >> 7;
  const int frow = lane & 15;
  const int fk16 = (lane >> 4) * 16;

  for (int kt = 0; kt < ksteps; ++kt) {
    stage_tile(A + kt * 64, lda, t, ldsA);
    stage_tile(Bm + kt * 64, ldb, t, ldsB);
    __syncthreads();
#pragma unroll
    for (int ki = 0; ki < 2; ++ki) {
      bf16x8 av[4], bv[4];
#pragma unroll
      for (int mi = 0; mi < 4; ++mi)
        av[mi] = frag_ld(ldsA, wm * 64 + mi * 16 + frow, ki * 64 + fk16);
#pragma unroll
      for (int ni = 0; ni < 4; ++ni)
        bv[ni] = frag_ld(ldsB, wn * 64 + ni * 16 + frow, ki * 64 + fk16);
#pragma unroll
      for (int mi = 0; mi < 4; ++mi)
#pragma unroll
        for (int ni = 0; ni < 4; ++ni)
          acc[mi][ni] = __builtin_amdgcn_mfma_f32_16x16x32_bf16(av[mi], bv[ni],
                                                                acc[mi][ni], 0, 0, 0);
    }
    __syncthreads();
  }
}

// ---------------- causal scores: Sc = Q K^T (lower-tri 128x128 tiles) --------
__global__ __launch_bounds__(256) void k_scores(const uint16_t* __restrict__ Qb,
                                                const uint16_t* __restrict__ Kb,
                                                float* __restrict__ Sc) {
  __shared__ __align__(16) char ldsA[16384];
  __shared__ __align__(16) char ldsB[16384];
  int x = blockIdx.x;                 // 0..543
  int b = x / 136, tr = x % 136;
  int qt = 0;
  while ((qt + 1) * (qt + 2) / 2 <= tr) ++qt;
  int kt = tr - qt * (qt + 1) / 2;

  f32x4 zero = {0.f, 0.f, 0.f, 0.f};
  f32x4 acc[4][4];
#pragma unroll
  for (int i = 0; i < 4; ++i)
#pragma unroll
    for (int j = 0; j < 4; ++j) acc[i][j] = zero;

  const uint16_t* A = Qb + ((size_t)b * SEQ + qt * 128) * DIM;
  const uint16_t* Bm = Kb + ((size_t)b * SEQ + kt * 128) * DIM;
  gemm_loop(A, DIM, Bm, DIM, DIM / 64, ldsA, ldsB, acc);

  const int lane = threadIdx.x & 63;
  const int wm = (threadIdx.x >> 6) & 1, wn = threadIdx.x >> 7;
  const int rbase = qt * 128 + wm * 64 + (lane >> 4) * 4;
  const int cbase = kt * 128 + wn * 64 + (lane & 15);
  float* out = Sc + (size_t)b * SEQ * SEQ;
#pragma unroll
  for (int mi = 0; mi < 4; ++mi)
#pragma unroll
    for (int ni = 0; ni < 4; ++ni) {
      int c = cbase + ni * 16;
#pragma unroll
      for (int r = 0; r < 4; ++r)
        out[(size_t)(rbase + mi * 16 + r) * SEQ + c] = acc[mi][ni][r];
    }
}

// ---------------- row softmax: one WAVE per row, row resident in registers ---
__global__ __launch_bounds__(256) void k_softmax(const float* __restrict__ Sc,
                                                 uint16_t* __restrict__ P) {
  int gid = blockIdx.x * 4 + (threadIdx.x >> 6);  // row id, 2048 blocks x 4 waves
  int lane = threadIdx.x & 63;
  int b = gid >> 11, q = gid & 2047;
  const float* srow = Sc + ((size_t)b * SEQ + q) * SEQ;
  uint16_t* prow = P + ((size_t)b * SEQ + q) * SEQ;
  int nv = q + 1;
  int kpad = ((q >> 7) + 1) << 7;                // PV reads exactly [0, kpad)
  int niter = (kpad + 255) >> 8;                 // 256 elems per wave-iter

  // load entire row into registers, mask invalid to -1e38 (exp -> 0)
  float4 v[8];
  const float4* src = (const float4*)srow;
#pragma unroll
  for (int i = 0; i < 8; ++i) {
    if (i < niter) {
      int idx = lane + (i << 6);
      float4 x = src[idx];
      int k0 = idx << 2;
      x.x = (k0 + 0 < nv) ? x.x : -1e38f;
      x.y = (k0 + 1 < nv) ? x.y : -1e38f;
      x.z = (k0 + 2 < nv) ? x.z : -1e38f;
      x.w = (k0 + 3 < nv) ? x.w : -1e38f;
      v[i] = x;
    } else {
      v[i] = make_float4(-1e38f, -1e38f, -1e38f, -1e38f);
    }
  }
  float m = -1e38f;
#pragma unroll
  for (int i = 0; i < 8; ++i)
    m = fmaxf(m, fmaxf(fmaxf(v[i].x, v[i].y), fmaxf(v[i].z, v[i].w)));
#pragma unroll
  for (int o = 32; o > 0; o >>= 1) m = fmaxf(m, __shfl_xor(m, o));

  float s = 0.f;
#pragma unroll
  for (int i = 0; i < 8; ++i) {
    v[i].x = __expf(v[i].x - m); v[i].y = __expf(v[i].y - m);
    v[i].z = __expf(v[i].z - m); v[i].w = __expf(v[i].w - m);
    s += v[i].x + v[i].y + v[i].z + v[i].w;
  }
#pragma unroll
  for (int o = 32; o > 0; o >>= 1) s += __shfl_xor(s, o);
  float inv = 1.0f / s;

  ushort4* dst = (ushort4*)prow;
#pragma unroll
  for (int i = 0; i < 8; ++i) {
    if (i < niter) {
      int idx = lane + (i << 6);
      if ((idx << 2) < kpad) {
        ushort4 o;
        o.x = f2bf(v[i].x * inv); o.y = f2bf(v[i].y * inv);
        o.z = f2bf(v[i].z * inv); o.w = f2bf(v[i].w * inv);
        dst[idx] = o;
      }
    }
  }
}

// ---------------- PV: O = P V  (A=P, B=Vt rows=e, cols=k) ----------------
__global__ __launch_bounds__(256) void k_pv(const uint16_t* __restrict__ P,
                                            const uint16_t* __restrict__ Vt,
                                            float* __restrict__ O) {
  __shared__ __align__(16) char ldsA[16384];
  __shared__ __align__(16) char ldsB[16384];
  int x = blockIdx.x;                 // 512
  int b = x >> 7, r7 = x & 127;
  int qt = 15 - (r7 >> 3);            // descending: big K-loops dispatch first
  int et = r7 & 7;

  f32x4 zero = {0.f, 0.f, 0.f, 0.f};
  f32x4 acc[4][4];
#pragma unroll
  for (int i = 0; i < 4; ++i)
#pragma unroll
    for (int j = 0; j < 4; ++j) acc[i][j] = zero;

  const uint16_t* A = P + (size_t)b * SEQ * SEQ + (size_t)qt * 128 * SEQ;
  const uint16_t* Bm = Vt + (size_t)b * DIM * SEQ + (size_t)et * 128 * SEQ;
  gemm_loop(A, SEQ, Bm, SEQ, (qt + 1) * 2, ldsA, ldsB, acc);

  const int lane = threadIdx.x & 63;
  const int wm = (threadIdx.x >> 6) & 1, wn = threadIdx.x >> 7;
  const int rbase = qt * 128 + wm * 64 + (lane >> 4) * 4;
  const int cbase = et * 128 + wn * 64 + (lane & 15);
  float* out = O + (size_t)b * SEQ * DIM;
#pragma unroll
  for (int mi = 0; mi < 4; ++mi)
#pragma unroll
    for (int ni = 0; ni < 4; ++ni) {
      int c = cbase + ni * 16;
#pragma unroll
      for (int r = 0; r < 4; ++r)
        out[(size_t)(rbase + mi * 16 + r) * DIM + c] = acc[mi][ni][r];
    }
}

extern "C" void kernel_launch(void* const* d_in, const int* in_sizes, int n_in,
                              void* d_out, int out_size, void* d_ws, size_t ws_size,
                              hipStream_t stream) {
  const float* X  = (const float*)d_in[0];
  const float* Wq = (const float*)d_in[1];
  const float* Wk = (const float*)d_in[2];
  const float* Wv = (const float*)d_in[3];
  char* ws = (char*)d_ws;
  uint16_t* Xbf = (uint16_t*)(ws + OFF_XBF);
  uint16_t* Wbf = (uint16_t*)(ws + OFF_WBF);
  uint16_t* Qb  = (uint16_t*)(ws + OFF_Q);
  uint16_t* Kb  = (uint16_t*)(ws + OFF_K);
  uint16_t* Vt  = (uint16_t*)(ws + OFF_VT);
  float*    Sc  = (float*)(ws + OFF_SC);
  uint16_t* P   = (uint16_t*)(ws + OFF_P);
  float*    O   = (float*)d_out;

  k_convert_x<<<8192, 256, 0, stream>>>(X, Xbf);
  k_convert_w<<<dim3(1024, 3), 256, 0, stream>>>(Wq, Wk, Wv, Wbf);
  k_qkv<<<dim3(64, 4, 3), 512, 98304, stream>>>(Xbf, Wbf, Qb, Kb, Vt);
  k_scores<<<544, 256, 0, stream>>>(Qb, Kb, Sc);
  k_softmax<<<2048, 256, 0, stream>>>(Sc, P);
  k_pv<<<512, 256, 0, stream>>>(P, Vt, O);
}

// Round 4
// 177.789 us; speedup vs baseline: 1.1149x; 1.0026x over previous
//
#include <hip/hip_runtime.h>
#include <hip/hip_bf16.h>
#include <stdint.h>

// Problem constants
#define NBATCH 4
#define SEQ    2048
#define DIM    1024

typedef __attribute__((ext_vector_type(8))) __bf16 bf16x8;
typedef __attribute__((ext_vector_type(4))) float  f32x4;

// Workspace layout (bytes)
#define OFF_XBF   (0ull)                         // 16 MiB
#define OFF_WBF   (16777216ull)                  //  6 MiB  [3072][1024] bf16
#define OFF_Q     (23068672ull)                  // 16 MiB (pre-scaled by 1/32)
#define OFF_K     (39845888ull)                  // 16 MiB
#define OFF_VT    (56623104ull)                  // 16 MiB  V^T per batch [DIM][SEQ]
#define OFF_SC    (73400320ull)                  // 64 MiB fp32 scores
#define OFF_P     (140509184ull)                 // 32 MiB bf16 probs

__device__ __forceinline__ uint16_t f2bf(float f) {
  uint32_t u = __float_as_uint(f);
  u = (u + 0x7fffu + ((u >> 16) & 1u)) >> 16;   // RTN-even
  return (uint16_t)u;
}

// ---------------- converts ----------------
__global__ __launch_bounds__(256) void k_convert_x(const float* __restrict__ X,
                                                   uint16_t* __restrict__ Xbf) {
  int i = blockIdx.x * 256 + threadIdx.x;
  float4 v = ((const float4*)X)[i];
  ushort4 o;
  o.x = f2bf(v.x); o.y = f2bf(v.y); o.z = f2bf(v.z); o.w = f2bf(v.w);
  ((ushort4*)Xbf)[i] = o;
}

__global__ __launch_bounds__(256) void k_convert_w(const float* __restrict__ Wq,
                                                   const float* __restrict__ Wk,
                                                   const float* __restrict__ Wv,
                                                   uint16_t* __restrict__ Wbf) {
  int g = blockIdx.y;
  const float* W = (g == 0) ? Wq : (g == 1) ? Wk : Wv;
  float scale = (g == 0) ? 0.03125f : 1.0f;     // fold 1/sqrt(1024) into W_q
  int i = blockIdx.x * 256 + threadIdx.x;
  float4 v = ((const float4*)W)[i];
  ushort4 o;
  o.x = f2bf(v.x * scale); o.y = f2bf(v.y * scale);
  o.z = f2bf(v.z * scale); o.w = f2bf(v.w * scale);
  ((ushort4*)(Wbf + (size_t)g * 1048576))[i] = o;
}

// ---------------- common helpers ----------------
// LDS rows are 64 bf16 = 128B; XOR swizzle byte ^= (row&7)<<4; inverse applied
// to the global SOURCE slot (global_load_lds writes linearly).

__device__ __forceinline__ void gll16(const void* g, void* l) {
  __builtin_amdgcn_global_load_lds((const __attribute__((address_space(1))) void*)g,
                                   (__attribute__((address_space(3))) void*)l, 16, 0, 0);
}

__device__ __forceinline__ bf16x8 frag_ld(const char* lds, int row, int kbyte) {
  int bo = row * 128 + kbyte;
  bo ^= (row & 7) << 4;
  return *(const bf16x8*)(lds + bo);
}

#define VM_WAIT8() asm volatile("s_waitcnt vmcnt(8)" ::: "memory")
#define VM_WAIT0() asm volatile("s_waitcnt vmcnt(0)" ::: "memory")
#define RAW_BAR()  asm volatile("s_barrier" ::: "memory")

// ---------------- 128^2 GEMM core: 2-deep counted-vmcnt pipeline -------------
// Ledger (8 loads/thread per tile = A4 + B4, uniform issue order across threads):
//   prologue: stage(0), stage(1)                      -> 16 loads outstanding
//   tile t entry: vmcnt(8) retires exactly stage(t); barrier => LDS visible
//   post-compute barrier => all reads of buf[t&1] done; then stage(t+2) -> WAR safe
__device__ __forceinline__ void stage_tile(const uint16_t* __restrict__ g, int ld,
                                           int t, char* lds) {
#pragma unroll
  for (int c = 0; c < 4; ++c) {
    int L = c * 4096 + t * 16;
    int row = L >> 7;
    int slot = (t & 7) ^ (row & 7);
    gll16((const void*)(g + (size_t)row * ld + slot * 8), (void*)(lds + L));
  }
}

__device__ __forceinline__ void gemm_loop(const uint16_t* __restrict__ A, int lda,
                                          const uint16_t* __restrict__ Bm, int ldb,
                                          int ksteps, char* lds, f32x4 acc[4][4]) {
  char* lA0 = lds;          char* lA1 = lds + 16384;
  char* lB0 = lds + 32768;  char* lB1 = lds + 49152;
  const int t = threadIdx.x;
  const int lane = t & 63;
  const int wm = (t >> 6) & 1;
  const int wn = t >> 7;
  const int frow = lane & 15;
  const int fk16 = (lane >> 4) * 16;

  stage_tile(A,      lda, t, lA0); stage_tile(Bm,      ldb, t, lB0);
  if (ksteps > 1) { stage_tile(A + 64, lda, t, lA1); stage_tile(Bm + 64, ldb, t, lB1); }

  for (int kt = 0; kt < ksteps; ++kt) {
    if (kt == ksteps - 1) { VM_WAIT0(); } else { VM_WAIT8(); }
    RAW_BAR();
    const char* cA = (kt & 1) ? lA1 : lA0;
    const char* cB = (kt & 1) ? lB1 : lB0;
#pragma unroll
    for (int ki = 0; ki < 2; ++ki) {
      bf16x8 av[4], bv[4];
#pragma unroll
      for (int mi = 0; mi < 4; ++mi)
        av[mi] = frag_ld(cA, wm * 64 + mi * 16 + frow, ki * 64 + fk16);
#pragma unroll
      for (int ni = 0; ni < 4; ++ni)
        bv[ni] = frag_ld(cB, wn * 64 + ni * 16 + frow, ki * 64 + fk16);
      __builtin_amdgcn_s_setprio(1);
#pragma unroll
      for (int mi = 0; mi < 4; ++mi)
#pragma unroll
        for (int ni = 0; ni < 4; ++ni)
          acc[mi][ni] = __builtin_amdgcn_mfma_f32_16x16x32_bf16(av[mi], bv[ni],
                                                                acc[mi][ni], 0, 0, 0);
      __builtin_amdgcn_s_setprio(0);
    }
    RAW_BAR();
    if (kt + 2 < ksteps) {
      stage_tile(A  + (kt + 2) * 64, lda, t, (kt & 1) ? lA1 : lA0);
      stage_tile(Bm + (kt + 2) * 64, ldb, t, (kt & 1) ? lB1 : lB0);
    }
  }
}

// ---------------- QKV projection: fused 8192x3072, 128^2 tiles, 2 blocks/CU --
__global__ __launch_bounds__(256) void k_qkv(const uint16_t* __restrict__ Xbf,
                                             const uint16_t* __restrict__ Wbf,
                                             uint16_t* __restrict__ Qb,
                                             uint16_t* __restrict__ Kb,
                                             uint16_t* __restrict__ Vt) {
  __shared__ __align__(16) char lds[65536];
  // 1536 blocks = 24 n-tiles x 64 m-tiles; bijective XCD swizzle (1536 = 8*192);
  // n-major so co-XCD blocks share the 256KB W panel in L2.
  int id = blockIdx.x;
  int lid = (id & 7) * 192 + (id >> 3);
  const int nt = lid >> 6, mt = lid & 63;
  const int m0 = mt * 128, n0 = nt * 128;
  const int g = n0 >> 10, ncol = n0 & 1023;

  f32x4 acc[4][4];
#pragma unroll
  for (int i = 0; i < 4; ++i)
#pragma unroll
    for (int j = 0; j < 4; ++j) acc[i][j] = (f32x4){0.f, 0.f, 0.f, 0.f};

  const uint16_t* A  = Xbf + (size_t)m0 * DIM;
  const uint16_t* Bm = Wbf + (size_t)n0 * DIM;  // Wbf as [3072][1024]
  gemm_loop(A, DIM, Bm, DIM, DIM / 64, lds, acc);

  const int lane = threadIdx.x & 63;
  const int wm = (threadIdx.x >> 6) & 1, wn = threadIdx.x >> 7;
  const int rbase = wm * 64 + (lane >> 4) * 4;  // C row = (lane>>4)*4 + reg
  const int cbase = wn * 64 + (lane & 15);      // C col = lane&15

  if (g < 2) {
    uint16_t* out = (g == 0) ? Qb : Kb;
#pragma unroll
    for (int mi = 0; mi < 4; ++mi)
#pragma unroll
      for (int ni = 0; ni < 4; ++ni) {
        int c = ncol + cbase + ni * 16;
#pragma unroll
        for (int r = 0; r < 4; ++r) {
          int m = m0 + rbase + mi * 16 + r;
          out[(size_t)m * DIM + c] = f2bf(acc[mi][ni][r]);
        }
      }
  } else {
    // write V transposed: Vt[b][e][s]
    const int b = m0 >> 11, sl = m0 & 2047;
#pragma unroll
    for (int mi = 0; mi < 4; ++mi)
#pragma unroll
      for (int ni = 0; ni < 4; ++ni) {
        int e = ncol + cbase + ni * 16;
        int s = sl + rbase + mi * 16;
        ushort4 o;
        o.x = f2bf(acc[mi][ni][0]); o.y = f2bf(acc[mi][ni][1]);
        o.z = f2bf(acc[mi][ni][2]); o.w = f2bf(acc[mi][ni][3]);
        *(ushort4*)(Vt + ((size_t)b * DIM + e) * SEQ + s) = o;
      }
  }
}

// ---------------- causal scores: Sc = Q K^T (lower-tri 128x128 tiles) --------
__global__ __launch_bounds__(256) void k_scores(const uint16_t* __restrict__ Qb,
                                                const uint16_t* __restrict__ Kb,
                                                float* __restrict__ Sc) {
  __shared__ __align__(16) char lds[65536];
  int x = blockIdx.x;                 // 0..543
  int b = x / 136, tr = x % 136;
  int qt = 0;
  while ((qt + 1) * (qt + 2) / 2 <= tr) ++qt;
  int kt = tr - qt * (qt + 1) / 2;

  f32x4 acc[4][4];
#pragma unroll
  for (int i = 0; i < 4; ++i)
#pragma unroll
    for (int j = 0; j < 4; ++j) acc[i][j] = (f32x4){0.f, 0.f, 0.f, 0.f};

  const uint16_t* A = Qb + ((size_t)b * SEQ + qt * 128) * DIM;
  const uint16_t* Bm = Kb + ((size_t)b * SEQ + kt * 128) * DIM;
  gemm_loop(A, DIM, Bm, DIM, DIM / 64, lds, acc);

  const int lane = threadIdx.x & 63;
  const int wm = (threadIdx.x >> 6) & 1, wn = threadIdx.x >> 7;
  const int rbase = qt * 128 + wm * 64 + (lane >> 4) * 4;
  const int cbase = kt * 128 + wn * 64 + (lane & 15);
  float* out = Sc + (size_t)b * SEQ * SEQ;
#pragma unroll
  for (int mi = 0; mi < 4; ++mi)
#pragma unroll
    for (int ni = 0; ni < 4; ++ni) {
      int c = cbase + ni * 16;
#pragma unroll
      for (int r = 0; r < 4; ++r)
        out[(size_t)(rbase + mi * 16 + r) * SEQ + c] = acc[mi][ni][r];
    }
}

// ---------------- row softmax: one WAVE per row, row in registers ------------
__global__ __launch_bounds__(256) void k_softmax(const float* __restrict__ Sc,
                                                 uint16_t* __restrict__ P) {
  int gid = blockIdx.x * 4 + (threadIdx.x >> 6);
  int lane = threadIdx.x & 63;
  int b = gid >> 11, q = gid & 2047;
  const float* srow = Sc + ((size_t)b * SEQ + q) * SEQ;
  uint16_t* prow = P + ((size_t)b * SEQ + q) * SEQ;
  int nv = q + 1;
  int kpad = ((q >> 7) + 1) << 7;
  int niter = (kpad + 255) >> 8;

  float4 v[8];
  const float4* src = (const float4*)srow;
#pragma unroll
  for (int i = 0; i < 8; ++i) {
    if (i < niter) {
      int idx = lane + (i << 6);
      float4 x = src[idx];
      int k0 = idx << 2;
      x.x = (k0 + 0 < nv) ? x.x : -1e38f;
      x.y = (k0 + 1 < nv) ? x.y : -1e38f;
      x.z = (k0 + 2 < nv) ? x.z : -1e38f;
      x.w = (k0 + 3 < nv) ? x.w : -1e38f;
      v[i] = x;
    } else {
      v[i] = make_float4(-1e38f, -1e38f, -1e38f, -1e38f);
    }
  }
  float m = -1e38f;
#pragma unroll
  for (int i = 0; i < 8; ++i)
    m = fmaxf(m, fmaxf(fmaxf(v[i].x, v[i].y), fmaxf(v[i].z, v[i].w)));
#pragma unroll
  for (int o = 32; o > 0; o >>= 1) m = fmaxf(m, __shfl_xor(m, o));

  float s = 0.f;
#pragma unroll
  for (int i = 0; i < 8; ++i) {
    v[i].x = __expf(v[i].x - m); v[i].y = __expf(v[i].y - m);
    v[i].z = __expf(v[i].z - m); v[i].w = __expf(v[i].w - m);
    s += v[i].x + v[i].y + v[i].z + v[i].w;
  }
#pragma unroll
  for (int o = 32; o > 0; o >>= 1) s += __shfl_xor(s, o);
  float inv = 1.0f / s;

  ushort4* dst = (ushort4*)prow;
#pragma unroll
  for (int i = 0; i < 8; ++i) {
    if (i < niter) {
      int idx = lane + (i << 6);
      if ((idx << 2) < kpad) {
        ushort4 o;
        o.x = f2bf(v[i].x * inv); o.y = f2bf(v[i].y * inv);
        o.z = f2bf(v[i].z * inv); o.w = f2bf(v[i].w * inv);
        dst[idx] = o;
      }
    }
  }
}

// ---------------- PV: O = P V  (A=P, B=Vt rows=e, cols=k) ----------------
__global__ __launch_bounds__(256) void k_pv(const uint16_t* __restrict__ P,
                                            const uint16_t* __restrict__ Vt,
                                            float* __restrict__ O) {
  __shared__ __align__(16) char lds[65536];
  int x = blockIdx.x;                 // 512
  int b = x >> 7, r7 = x & 127;
  int qt = 15 - (r7 >> 3);            // descending: big K-loops dispatch first
  int et = r7 & 7;

  f32x4 acc[4][4];
#pragma unroll
  for (int i = 0; i < 4; ++i)
#pragma unroll
    for (int j = 0; j < 4; ++j) acc[i][j] = (f32x4){0.f, 0.f, 0.f, 0.f};

  const uint16_t* A = P + (size_t)b * SEQ * SEQ + (size_t)qt * 128 * SEQ;
  const uint16_t* Bm = Vt + (size_t)b * DIM * SEQ + (size_t)et * 128 * SEQ;
  gemm_loop(A, SEQ, Bm, SEQ, (qt + 1) * 2, lds, acc);

  const int lane = threadIdx.x & 63;
  const int wm = (threadIdx.x >> 6) & 1, wn = threadIdx.x >> 7;
  const int rbase = qt * 128 + wm * 64 + (lane >> 4) * 4;
  const int cbase = et * 128 + wn * 64 + (lane & 15);
  float* out = O + (size_t)b * SEQ * DIM;
#pragma unroll
  for (int mi = 0; mi < 4; ++mi)
#pragma unroll
    for (int ni = 0; ni < 4; ++ni) {
      int c = cbase + ni * 16;
#pragma unroll
      for (int r = 0; r < 4; ++r)
        out[(size_t)(rbase + mi * 16 + r) * DIM + c] = acc[mi][ni][r];
    }
}

extern "C" void kernel_launch(void* const* d_in, const int* in_sizes, int n_in,
                              void* d_out, int out_size, void* d_ws, size_t ws_size,
                              hipStream_t stream) {
  const float* X  = (const float*)d_in[0];
  const float* Wq = (const float*)d_in[1];
  const float* Wk = (const float*)d_in[2];
  const float* Wv = (const float*)d_in[3];
  char* ws = (char*)d_ws;
  uint16_t* Xbf = (uint16_t*)(ws + OFF_XBF);
  uint16_t* Wbf = (uint16_t*)(ws + OFF_WBF);
  uint16_t* Qb  = (uint16_t*)(ws + OFF_Q);
  uint16_t* Kb  = (uint16_t*)(ws + OFF_K);
  uint16_t* Vt  = (uint16_t*)(ws + OFF_VT);
  float*    Sc  = (float*)(ws + OFF_SC);
  uint16_t* P   = (uint16_t*)(ws + OFF_P);
  float*    O   = (float*)d_out;

  k_convert_x<<<8192, 256, 0, stream>>>(X, Xbf);
  k_convert_w<<<dim3(1024, 3), 256, 0, stream>>>(Wq, Wk, Wv, Wbf);
  k_qkv<<<1536, 256, 0, stream>>>(Xbf, Wbf, Qb, Kb, Vt);
  k_scores<<<544, 256, 0, stream>>>(Qb, Kb, Sc);
  k_softmax<<<2048, 256, 0, stream>>>(Sc, P);
  k_pv<<<512, 256, 0, stream>>>(P, Vt, O);
}

// Round 5
// 160.479 us; speedup vs baseline: 1.2351x; 1.1079x over previous
//
#include <hip/hip_runtime.h>
#include <hip/hip_bf16.h>
#include <hip/hip_fp16.h>
#include <stdint.h>

// Problem constants
#define NBATCH 4
#define SEQ    2048
#define DIM    1024

typedef __attribute__((ext_vector_type(8))) __bf16 bf16x8;
typedef __attribute__((ext_vector_type(4))) float  f32x4;

// Workspace layout (bytes)
#define OFF_XBF   (0ull)                         // 16 MiB
#define OFF_WBF   (16777216ull)                  //  6 MiB  [3072][1024] bf16
#define OFF_Q     (23068672ull)                  // 16 MiB (pre-scaled by 1/32)
#define OFF_K     (39845888ull)                  // 16 MiB
#define OFF_VT    (56623104ull)                  // 16 MiB  V^T per batch [DIM][SEQ]
#define OFF_SC    (73400320ull)                  // 32 MiB fp16 scores
#define OFF_P     (140509184ull)                 // 32 MiB bf16 probs

__device__ __forceinline__ uint16_t f2bf(float f) {
  uint32_t u = __float_as_uint(f);
  u = (u + 0x7fffu + ((u >> 16) & 1u)) >> 16;   // RTN-even
  return (uint16_t)u;
}

// ---------------- fused converts: X (blocks 0..8191), W (blocks 8192..11263) --
__global__ __launch_bounds__(256) void k_convert(const float* __restrict__ X,
                                                 const float* __restrict__ Wq,
                                                 const float* __restrict__ Wk,
                                                 const float* __restrict__ Wv,
                                                 uint16_t* __restrict__ Xbf,
                                                 uint16_t* __restrict__ Wbf) {
  int id = blockIdx.x;
  if (id < 8192) {
    int i = id * 256 + threadIdx.x;
    float4 v = ((const float4*)X)[i];
    ushort4 o;
    o.x = f2bf(v.x); o.y = f2bf(v.y); o.z = f2bf(v.z); o.w = f2bf(v.w);
    ((ushort4*)Xbf)[i] = o;
  } else {
    int j = id - 8192;                    // 0..3071
    int g = j >> 10;
    const float* W = (g == 0) ? Wq : (g == 1) ? Wk : Wv;
    float scale = (g == 0) ? 0.03125f : 1.0f;   // fold 1/sqrt(1024) into W_q
    int i = (j & 1023) * 256 + threadIdx.x;
    float4 v = ((const float4*)W)[i];
    ushort4 o;
    o.x = f2bf(v.x * scale); o.y = f2bf(v.y * scale);
    o.z = f2bf(v.z * scale); o.w = f2bf(v.w * scale);
    ((ushort4*)(Wbf + (size_t)g * 1048576))[i] = o;
  }
}

// ---------------- common helpers ----------------
// LDS rows are 64 bf16 = 128B; XOR swizzle byte ^= (row&7)<<4; inverse applied
// to the global SOURCE slot (global_load_lds writes linearly).

__device__ __forceinline__ void gll16(const void* g, void* l) {
  __builtin_amdgcn_global_load_lds((const __attribute__((address_space(1))) void*)g,
                                   (__attribute__((address_space(3))) void*)l, 16, 0, 0);
}

__device__ __forceinline__ bf16x8 frag_ld(const char* lds, int row, int kbyte) {
  int bo = row * 128 + kbyte;
  bo ^= (row & 7) << 4;
  return *(const bf16x8*)(lds + bo);
}

#define VM_WAIT8() asm volatile("s_waitcnt vmcnt(8)" ::: "memory")
#define VM_WAIT0() asm volatile("s_waitcnt vmcnt(0)" ::: "memory")
#define RAW_BAR()  asm volatile("s_barrier" ::: "memory")

// ---------------- 128^2 GEMM core: 2-deep counted-vmcnt pipeline -------------
// Ledger (8 loads/thread per tile = A4 + B4, uniform issue order across threads):
//   prologue: stage(0), stage(1)                      -> 16 loads outstanding
//   tile t entry: vmcnt(8) retires exactly stage(t); barrier => LDS visible
//   post-compute barrier => all reads of buf[t&1] done; then stage(t+2) -> WAR safe
__device__ __forceinline__ void stage_tile(const uint16_t* __restrict__ g, int ld,
                                           int t, char* lds) {
#pragma unroll
  for (int c = 0; c < 4; ++c) {
    int L = c * 4096 + t * 16;
    int row = L >> 7;
    int slot = (t & 7) ^ (row & 7);
    gll16((const void*)(g + (size_t)row * ld + slot * 8), (void*)(lds + L));
  }
}

__device__ __forceinline__ void gemm_loop(const uint16_t* __restrict__ A, int lda,
                                          const uint16_t* __restrict__ Bm, int ldb,
                                          int ksteps, char* lds, f32x4 acc[4][4]) {
  char* lA0 = lds;          char* lA1 = lds + 16384;
  char* lB0 = lds + 32768;  char* lB1 = lds + 49152;
  const int t = threadIdx.x;
  const int lane = t & 63;
  const int wm = (t >> 6) & 1;
  const int wn = t >> 7;
  const int frow = lane & 15;
  const int fk16 = (lane >> 4) * 16;

  stage_tile(A,      lda, t, lA0); stage_tile(Bm,      ldb, t, lB0);
  if (ksteps > 1) { stage_tile(A + 64, lda, t, lA1); stage_tile(Bm + 64, ldb, t, lB1); }

  for (int kt = 0; kt < ksteps; ++kt) {
    if (kt == ksteps - 1) { VM_WAIT0(); } else { VM_WAIT8(); }
    RAW_BAR();
    const char* cA = (kt & 1) ? lA1 : lA0;
    const char* cB = (kt & 1) ? lB1 : lB0;
#pragma unroll
    for (int ki = 0; ki < 2; ++ki) {
      bf16x8 av[4], bv[4];
#pragma unroll
      for (int mi = 0; mi < 4; ++mi)
        av[mi] = frag_ld(cA, wm * 64 + mi * 16 + frow, ki * 64 + fk16);
#pragma unroll
      for (int ni = 0; ni < 4; ++ni)
        bv[ni] = frag_ld(cB, wn * 64 + ni * 16 + frow, ki * 64 + fk16);
      __builtin_amdgcn_s_setprio(1);
#pragma unroll
      for (int mi = 0; mi < 4; ++mi)
#pragma unroll
        for (int ni = 0; ni < 4; ++ni)
          acc[mi][ni] = __builtin_amdgcn_mfma_f32_16x16x32_bf16(av[mi], bv[ni],
                                                                acc[mi][ni], 0, 0, 0);
      __builtin_amdgcn_s_setprio(0);
    }
    RAW_BAR();
    if (kt + 2 < ksteps) {
      stage_tile(A  + (kt + 2) * 64, lda, t, (kt & 1) ? lA1 : lA0);
      stage_tile(Bm + (kt + 2) * 64, ldb, t, (kt & 1) ? lB1 : lB0);
    }
  }
}

// ---------------- QKV projection: fused 8192x3072, 128^2 tiles, 2 blocks/CU --
// Grid 1536 = 64 m x 24 n, m-FASTEST, no swizzle: id = mt + 64*nt.
// Round-robin dispatch => id mod 8 = XCD, and 64*nt mod 8 == 0, so each XCD
// only ever touches m-tiles with mt mod 8 == xcd: 2MB X-slice + ~2MB W in-flight
// stays L2-resident (this is what kept R2's FETCH at 49MB; R4's swizzle broke it).
__global__ __launch_bounds__(256) void k_qkv(const uint16_t* __restrict__ Xbf,
                                             const uint16_t* __restrict__ Wbf,
                                             uint16_t* __restrict__ Qb,
                                             uint16_t* __restrict__ Kb,
                                             uint16_t* __restrict__ Vt) {
  __shared__ __align__(16) char lds[65536];
  int id = blockIdx.x;
  const int mt = id & 63, nt = id >> 6;
  const int m0 = mt * 128, n0 = nt * 128;
  const int g = n0 >> 10, ncol = n0 & 1023;

  f32x4 acc[4][4];
#pragma unroll
  for (int i = 0; i < 4; ++i)
#pragma unroll
    for (int j = 0; j < 4; ++j) acc[i][j] = (f32x4){0.f, 0.f, 0.f, 0.f};

  const uint16_t* A  = Xbf + (size_t)m0 * DIM;
  const uint16_t* Bm = Wbf + (size_t)n0 * DIM;  // Wbf as [3072][1024]
  gemm_loop(A, DIM, Bm, DIM, DIM / 64, lds, acc);

  const int lane = threadIdx.x & 63;
  const int wm = (threadIdx.x >> 6) & 1, wn = threadIdx.x >> 7;
  const int rbase = wm * 64 + (lane >> 4) * 4;  // C row = (lane>>4)*4 + reg
  const int cbase = wn * 64 + (lane & 15);      // C col = lane&15

  if (g < 2) {
    uint16_t* out = (g == 0) ? Qb : Kb;
#pragma unroll
    for (int mi = 0; mi < 4; ++mi)
#pragma unroll
      for (int ni = 0; ni < 4; ++ni) {
        int c = ncol + cbase + ni * 16;
#pragma unroll
        for (int r = 0; r < 4; ++r) {
          int m = m0 + rbase + mi * 16 + r;
          out[(size_t)m * DIM + c] = f2bf(acc[mi][ni][r]);
        }
      }
  } else {
    // write V transposed: Vt[b][e][s]
    const int b = m0 >> 11, sl = m0 & 2047;
#pragma unroll
    for (int mi = 0; mi < 4; ++mi)
#pragma unroll
      for (int ni = 0; ni < 4; ++ni) {
        int e = ncol + cbase + ni * 16;
        int s = sl + rbase + mi * 16;
        ushort4 o;
        o.x = f2bf(acc[mi][ni][0]); o.y = f2bf(acc[mi][ni][1]);
        o.z = f2bf(acc[mi][ni][2]); o.w = f2bf(acc[mi][ni][3]);
        *(ushort4*)(Vt + ((size_t)b * DIM + e) * SEQ + s) = o;
      }
  }
}

// ---------------- causal scores: Sc = Q K^T (lower-tri 128x128 tiles, fp16) --
__global__ __launch_bounds__(256) void k_scores(const uint16_t* __restrict__ Qb,
                                                const uint16_t* __restrict__ Kb,
                                                __half* __restrict__ Sc) {
  __shared__ __align__(16) char lds[65536];
  int x = blockIdx.x;                 // 0..543
  int b = x / 136, tr = x % 136;
  int qt = 0;
  while ((qt + 1) * (qt + 2) / 2 <= tr) ++qt;
  int kt = tr - qt * (qt + 1) / 2;

  f32x4 acc[4][4];
#pragma unroll
  for (int i = 0; i < 4; ++i)
#pragma unroll
    for (int j = 0; j < 4; ++j) acc[i][j] = (f32x4){0.f, 0.f, 0.f, 0.f};

  const uint16_t* A = Qb + ((size_t)b * SEQ + qt * 128) * DIM;
  const uint16_t* Bm = Kb + ((size_t)b * SEQ + kt * 128) * DIM;
  gemm_loop(A, DIM, Bm, DIM, DIM / 64, lds, acc);

  const int lane = threadIdx.x & 63;
  const int wm = (threadIdx.x >> 6) & 1, wn = threadIdx.x >> 7;
  const int rbase = qt * 128 + wm * 64 + (lane >> 4) * 4;
  const int cbase = kt * 128 + wn * 64 + (lane & 15);
  __half* out = Sc + (size_t)b * SEQ * SEQ;
#pragma unroll
  for (int mi = 0; mi < 4; ++mi)
#pragma unroll
    for (int ni = 0; ni < 4; ++ni) {
      int c = cbase + ni * 16;
#pragma unroll
      for (int r = 0; r < 4; ++r)
        out[(size_t)(rbase + mi * 16 + r) * SEQ + c] = __float2half(acc[mi][ni][r]);
    }
}

// ---------------- row softmax: one WAVE per row, fp16 row in registers -------
struct h4 { __half2 a, b; };          // 8 bytes = 4 halves

__global__ __launch_bounds__(256) void k_softmax(const __half* __restrict__ Sc,
                                                 uint16_t* __restrict__ P) {
  int gid = blockIdx.x * 4 + (threadIdx.x >> 6);
  int lane = threadIdx.x & 63;
  int b = gid >> 11, q = gid & 2047;
  const __half* srow = Sc + ((size_t)b * SEQ + q) * SEQ;
  uint16_t* prow = P + ((size_t)b * SEQ + q) * SEQ;
  int nv = q + 1;
  int kpad = ((q >> 7) + 1) << 7;     // PV reads exactly [0, kpad)
  int niter = (kpad + 255) >> 8;      // 256 halves per wave-iter

  float4 v[8];
  const h4* src = (const h4*)srow;
#pragma unroll
  for (int i = 0; i < 8; ++i) {
    if (i < niter) {
      int idx = lane + (i << 6);
      h4 raw = src[idx];
      float2 fa = __half22float2(raw.a), fb = __half22float2(raw.b);
      int k0 = idx << 2;
      float4 x;
      x.x = (k0 + 0 < nv) ? fa.x : -1e38f;
      x.y = (k0 + 1 < nv) ? fa.y : -1e38f;
      x.z = (k0 + 2 < nv) ? fb.x : -1e38f;
      x.w = (k0 + 3 < nv) ? fb.y : -1e38f;
      v[i] = x;
    } else {
      v[i] = make_float4(-1e38f, -1e38f, -1e38f, -1e38f);
    }
  }
  float m = -1e38f;
#pragma unroll
  for (int i = 0; i < 8; ++i)
    m = fmaxf(m, fmaxf(fmaxf(v[i].x, v[i].y), fmaxf(v[i].z, v[i].w)));
#pragma unroll
  for (int o = 32; o > 0; o >>= 1) m = fmaxf(m, __shfl_xor(m, o));

  float s = 0.f;
#pragma unroll
  for (int i = 0; i < 8; ++i) {
    v[i].x = __expf(v[i].x - m); v[i].y = __expf(v[i].y - m);
    v[i].z = __expf(v[i].z - m); v[i].w = __expf(v[i].w - m);
    s += v[i].x + v[i].y + v[i].z + v[i].w;
  }
#pragma unroll
  for (int o = 32; o > 0; o >>= 1) s += __shfl_xor(s, o);
  float inv = 1.0f / s;

  ushort4* dst = (ushort4*)prow;
#pragma unroll
  for (int i = 0; i < 8; ++i) {
    if (i < niter) {
      int idx = lane + (i << 6);
      if ((idx << 2) < kpad) {
        ushort4 o;
        o.x = f2bf(v[i].x * inv); o.y = f2bf(v[i].y * inv);
        o.z = f2bf(v[i].z * inv); o.w = f2bf(v[i].w * inv);
        dst[idx] = o;
      }
    }
  }
}

// ---------------- PV: O = P V  (A=P, B=Vt rows=e, cols=k) ----------------
__global__ __launch_bounds__(256) void k_pv(const uint16_t* __restrict__ P,
                                            const uint16_t* __restrict__ Vt,
                                            float* __restrict__ O) {
  __shared__ __align__(16) char lds[65536];
  int x = blockIdx.x;                 // 512
  int b = x >> 7, r7 = x & 127;
  int qt = 15 - (r7 >> 3);            // descending: big K-loops dispatch first
  int et = r7 & 7;

  f32x4 acc[4][4];
#pragma unroll
  for (int i = 0; i < 4; ++i)
#pragma unroll
    for (int j = 0; j < 4; ++j) acc[i][j] = (f32x4){0.f, 0.f, 0.f, 0.f};

  const uint16_t* A = P + (size_t)b * SEQ * SEQ + (size_t)qt * 128 * SEQ;
  const uint16_t* Bm = Vt + (size_t)b * DIM * SEQ + (size_t)et * 128 * SEQ;
  gemm_loop(A, SEQ, Bm, SEQ, (qt + 1) * 2, lds, acc);

  const int lane = threadIdx.x & 63;
  const int wm = (threadIdx.x >> 6) & 1, wn = threadIdx.x >> 7;
  const int rbase = qt * 128 + wm * 64 + (lane >> 4) * 4;
  const int cbase = et * 128 + wn * 64 + (lane & 15);
  float* out = O + (size_t)b * SEQ * DIM;
#pragma unroll
  for (int mi = 0; mi < 4; ++mi)
#pragma unroll
    for (int ni = 0; ni < 4; ++ni) {
      int c = cbase + ni * 16;
#pragma unroll
      for (int r = 0; r < 4; ++r)
        out[(size_t)(rbase + mi * 16 + r) * DIM + c] = acc[mi][ni][r];
    }
}

extern "C" void kernel_launch(void* const* d_in, const int* in_sizes, int n_in,
                              void* d_out, int out_size, void* d_ws, size_t ws_size,
                              hipStream_t stream) {
  const float* X  = (const float*)d_in[0];
  const float* Wq = (const float*)d_in[1];
  const float* Wk = (const float*)d_in[2];
  const float* Wv = (const float*)d_in[3];
  char* ws = (char*)d_ws;
  uint16_t* Xbf = (uint16_t*)(ws + OFF_XBF);
  uint16_t* Wbf = (uint16_t*)(ws + OFF_WBF);
  uint16_t* Qb  = (uint16_t*)(ws + OFF_Q);
  uint16_t* Kb  = (uint16_t*)(ws + OFF_K);
  uint16_t* Vt  = (uint16_t*)(ws + OFF_VT);
  __half*   Sc  = (__half*)(ws + OFF_SC);
  uint16_t* P   = (uint16_t*)(ws + OFF_P);
  float*    O   = (float*)d_out;

  k_convert<<<11264, 256, 0, stream>>>(X, Wq, Wk, Wv, Xbf, Wbf);
  k_qkv<<<1536, 256, 0, stream>>>(Xbf, Wbf, Qb, Kb, Vt);
  k_scores<<<544, 256, 0, stream>>>(Qb, Kb, Sc);
  k_softmax<<<2048, 256, 0, stream>>>(Sc, P);
  k_pv<<<512, 256, 0, stream>>>(P, Vt, O);
}